// Round 8
// baseline (316.748 us; speedup 1.0000x reference)
//
#include <hip/hip_runtime.h>
#include <math.h>

typedef __bf16 bf16;
typedef __attribute__((ext_vector_type(8))) __bf16 bf16x8;
typedef __attribute__((ext_vector_type(4))) float f32x4;
typedef __attribute__((ext_vector_type(8))) int i32x8;

typedef __attribute__((address_space(1))) const void gvoid;
typedef __attribute__((address_space(3))) void lvoid;
#define GLL(g, l) __builtin_amdgcn_global_load_lds((gvoid*)(g), (lvoid*)(l), 16, 0, 0)
#define MFMA(a, b, c) __builtin_amdgcn_mfma_f32_16x16x32_bf16((a), (b), (c), 0, 0, 0)
// MX-scaled fp8 GEMM, unit scales (E8M0 0x7F = 1.0): exact same math as fp8_fp8, 2.28x rate
#define MFMAS(a, b, c) \
  __builtin_amdgcn_mfma_scale_f32_16x16x128_f8f6f4((a), (b), (c), 0, 0, 0, 0x7F, 0, 0x7F)

__device__ __forceinline__ int swz128(int row, int kb) { return kb ^ ((row & 7) << 4); }

// ---- fp8 e4m3fn encode/decode (OCP: bias 7, max 448, no inf) ----
__device__ __forceinline__ unsigned char f32_to_e4m3(float x) {
  const unsigned s = (__float_as_uint(x) >> 24) & 0x80;
  float ax = fminf(fabsf(x), 448.f);
  unsigned e;
  if (ax >= 0.015625f) {  // normal range (>= 2^-6)
    const unsigned u = __float_as_uint(ax);
    const unsigned t = u + 0x7FFFF + ((u >> 20) & 1);  // RNE to 3 mantissa bits
    e = (((t >> 23) - 120) << 3) | ((t >> 20) & 7);
  } else {  // subnormal: value = q * 2^-9, q in 0..8
    e = (unsigned)__float2int_rn(ax * 512.f);
  }
  return (unsigned char)(s | e);
}
__device__ __forceinline__ float e4m3_to_f32(unsigned char b) {
  const unsigned s = ((unsigned)b & 0x80) << 24;
  const unsigned em = b & 0x7F;
  float v;
  if (em >= 8) v = __uint_as_float((((em >> 3) + 120) << 23) | ((em & 7) << 20));
  else v = (float)em * 0.001953125f;
  return __uint_as_float(__float_as_uint(v) | s);
}

// ---------------- prep: W1 [1024][512] -> W1t bf16 [512][1024]; W2 [512][256] -> W2t [256][512]
__global__ __launch_bounds__(256) void prep_w(const float* __restrict__ W1,
                                              const float* __restrict__ W2,
                                              bf16* __restrict__ W1t, bf16* __restrict__ W2t) {
  const int t = blockIdx.x * 256 + threadIdx.x;
  if (t < 512 * 1024) {
    const int h = t & 511, k = t >> 9;
    W1t[h * 1024 + k] = (bf16)W1[k * 512 + h];
  } else {
    const int u = t - 512 * 1024;
    const int e = u & 255, k = u >> 8;
    W2t[e * 512 + k] = (bf16)W2[k * 256 + e];
  }
}

// ---------------- prep: bank fp32 [16384][256] -> SB8 = e4m3(-2*bank) repacked as a
// per-(tile, wave, half, lane) register-fragment stream:
//   SB8[(((t*8+w)*2+h)*64 + lk*16 + lr)*32 + (k & 31)]  holds bank row (t*128+w*16+lr),
//   k = h*128 + lk*32 + [0,32)  -- one i32x8 load per lane per half, fully coalesced.
// m2[row] consistent with the quantized values used in MFMA.
__global__ __launch_bounds__(256) void prep_bank(const float* __restrict__ bank,
                                                 unsigned char* __restrict__ SB8,
                                                 float* __restrict__ m2) {
  const int tid = threadIdx.x, lane = tid & 63, wv = tid >> 6;
  const int row = blockIdx.x * 4 + wv;
  const float4 v = *reinterpret_cast<const float4*>(bank + (size_t)row * 256 + lane * 4);
  uchar4 q;
  float ssum = 0.f;
  {
    const float xs[4] = {v.x, v.y, v.z, v.w};
    unsigned char qb[4];
#pragma unroll
    for (int e = 0; e < 4; ++e) {
      qb[e] = f32_to_e4m3(-2.f * xs[e]);
      const float d = e4m3_to_f32(qb[e]);
      ssum += d * d;
    }
    q.x = qb[0]; q.y = qb[1]; q.z = qb[2]; q.w = qb[3];
  }
#pragma unroll
  for (int off = 1; off < 64; off <<= 1) ssum += __shfl_xor(ssum, off);
  // k0 = lane*4: h = k0>>7, lk = (k0>>5)&3, off32 = k0&31
  const int t = row >> 7, ww = (row >> 4) & 7, lrr = row & 15;
  const int h = lane >> 5, lk = (lane >> 3) & 3, off32 = (lane & 7) * 4;
  const size_t dst = ((((size_t)t * 8 + ww) * 2 + h) * 64 + lk * 16 + lrr) * 32 + off32;
  *reinterpret_cast<uchar4*>(SB8 + dst) = q;
  if (lane == 0) m2[row] = ssum * 0.25f;  // (d/2)^2 summed
}

// ---------------- mlp1: H[32768][512] = relu(F @ W1 + b1), bf16 out
__global__ __launch_bounds__(512, 2) void mlp1_kernel(const float* __restrict__ F,
                                                      const bf16* __restrict__ W1t,
                                                      const float* __restrict__ b1,
                                                      bf16* __restrict__ H) {
  __shared__ __align__(16) char smem[81920];
  char* sA = smem;          // F chunk bf16 [128 rows][128B], swizzled
  char* sB = smem + 16384;  // W1t chunk [512 n][128B], swizzled

  const int tid = threadIdx.x;
  const int w = tid >> 6, lane = tid & 63;
  const int wm = w >> 2, wn = w & 3;
  const int lr = lane & 15, lk = lane >> 4;
  const size_t r0 = (size_t)blockIdx.x * 128;

  f32x4 acc[4][8];
  const f32x4 z = {0.f, 0.f, 0.f, 0.f};
#pragma unroll
  for (int m = 0; m < 4; ++m)
#pragma unroll
    for (int n = 0; n < 8; ++n) acc[m][n] = z;

  for (int kc = 0; kc < 16; ++kc) {
    {
      const int fr = tid >> 2, kg = (tid & 3) << 4;
      const float* fsrc = F + (r0 + fr) * 1024 + kc * 64 + kg;
      const float4 f0 = *reinterpret_cast<const float4*>(fsrc);
      const float4 f1 = *reinterpret_cast<const float4*>(fsrc + 4);
      const float4 f2 = *reinterpret_cast<const float4*>(fsrc + 8);
      const float4 f3 = *reinterpret_cast<const float4*>(fsrc + 12);
      bf16x8 p0, p1;
      p0[0] = (bf16)f0.x; p0[1] = (bf16)f0.y; p0[2] = (bf16)f0.z; p0[3] = (bf16)f0.w;
      p0[4] = (bf16)f1.x; p0[5] = (bf16)f1.y; p0[6] = (bf16)f1.z; p0[7] = (bf16)f1.w;
      p1[0] = (bf16)f2.x; p1[1] = (bf16)f2.y; p1[2] = (bf16)f2.z; p1[3] = (bf16)f2.w;
      p1[4] = (bf16)f3.x; p1[5] = (bf16)f3.y; p1[6] = (bf16)f3.z; p1[7] = (bf16)f3.w;
      const int bb = kg * 2;
      *(bf16x8*)(sA + fr * 128 + swz128(fr, bb)) = p0;
      *(bf16x8*)(sA + fr * 128 + swz128(fr, bb + 16)) = p1;
    }
#pragma unroll
    for (int i = 0; i < 8; ++i) {
      const int o = (w * 8 + i) * 1024 + lane * 16;
      const int n = o >> 7, b = o & 127;
      GLL((const char*)W1t + n * 2048 + kc * 128 + swz128(n, b), sB + (w * 8 + i) * 1024);
    }
    __syncthreads();
#pragma unroll
    for (int ks = 0; ks < 2; ++ks) {
      bf16x8 av[4];
#pragma unroll
      for (int Mt = 0; Mt < 4; ++Mt) {
        const int row = wm * 64 + Mt * 16 + lr;
        av[Mt] = *(const bf16x8*)(sA + row * 128 + swz128(row, ks * 64 + lk * 16));
      }
#pragma unroll
      for (int Nt = 0; Nt < 8; ++Nt) {
        const int n = wn * 128 + Nt * 16 + lr;
        const bf16x8 bv = *(const bf16x8*)(sB + n * 128 + swz128(n, ks * 64 + lk * 16));
#pragma unroll
        for (int Mt = 0; Mt < 4; ++Mt) acc[Mt][Nt] = MFMA(av[Mt], bv, acc[Mt][Nt]);
      }
    }
    __syncthreads();
  }
#pragma unroll
  for (int Nt = 0; Nt < 8; ++Nt) {
    const int col = wn * 128 + Nt * 16 + lr;
    const float bias = b1[col];
#pragma unroll
    for (int Mt = 0; Mt < 4; ++Mt) {
      const size_t rowb = r0 + wm * 64 + Mt * 16 + lk * 4;
#pragma unroll
      for (int q = 0; q < 4; ++q)
        H[(rowb + q) * 512 + col] = (bf16)fmaxf(acc[Mt][Nt][q] + bias, 0.f);
    }
  }
}

// ---------------- mlp2: PROJ8[32768][256] fp8 = e4m3(H @ W2 + b2); X2 from decoded fp8
__global__ __launch_bounds__(512, 2) void mlp2_kernel(const bf16* __restrict__ H,
                                                      const bf16* __restrict__ W2t,
                                                      const float* __restrict__ b2,
                                                      unsigned char* __restrict__ PROJ8,
                                                      float* __restrict__ X2) {
  __shared__ __align__(16) char smem[51200];
  char* sA = smem;                        // H chunk [128][128B] swizzled
  char* sB = smem + 16384;                // W2t chunk [256][128B] swizzled
  float* sX2 = (float*)(smem + 49152);    // [4][128]

  const int tid = threadIdx.x;
  const int w = tid >> 6, lane = tid & 63;
  const int wm = w >> 2, wn = w & 3;
  const int lr = lane & 15, lk = lane >> 4;
  const size_t r0 = (size_t)blockIdx.x * 128;

  f32x4 acc[4][4];
  const f32x4 z = {0.f, 0.f, 0.f, 0.f};
#pragma unroll
  for (int m = 0; m < 4; ++m)
#pragma unroll
    for (int n = 0; n < 4; ++n) acc[m][n] = z;

  for (int kc = 0; kc < 8; ++kc) {
#pragma unroll
    for (int i = 0; i < 2; ++i) {
      const int o = (w * 2 + i) * 1024 + lane * 16;
      const int row = o >> 7, b = o & 127;
      GLL((const char*)H + (r0 + row) * 1024 + kc * 128 + swz128(row, b), sA + (w * 2 + i) * 1024);
    }
#pragma unroll
    for (int i = 0; i < 4; ++i) {
      const int o = (w * 4 + i) * 1024 + lane * 16;
      const int n = o >> 7, b = o & 127;
      GLL((const char*)W2t + n * 1024 + kc * 128 + swz128(n, b), sB + (w * 4 + i) * 1024);
    }
    __syncthreads();
#pragma unroll
    for (int ks = 0; ks < 2; ++ks) {
      bf16x8 av[4];
#pragma unroll
      for (int Mt = 0; Mt < 4; ++Mt) {
        const int row = wm * 64 + Mt * 16 + lr;
        av[Mt] = *(const bf16x8*)(sA + row * 128 + swz128(row, ks * 64 + lk * 16));
      }
#pragma unroll
      for (int Nt = 0; Nt < 4; ++Nt) {
        const int n = wn * 64 + Nt * 16 + lr;
        const bf16x8 bv = *(const bf16x8*)(sB + n * 128 + swz128(n, ks * 64 + lk * 16));
#pragma unroll
        for (int Mt = 0; Mt < 4; ++Mt) acc[Mt][Nt] = MFMA(av[Mt], bv, acc[Mt][Nt]);
      }
    }
    __syncthreads();
  }
  // epilogue: +b2, quantize to fp8, store PROJ8, accumulate consistent x2
  float x2p[4][4];
#pragma unroll
  for (int m = 0; m < 4; ++m)
#pragma unroll
    for (int q = 0; q < 4; ++q) x2p[m][q] = 0.f;
#pragma unroll
  for (int Nt = 0; Nt < 4; ++Nt) {
    const int col = wn * 64 + Nt * 16 + lr;
    const float bias = b2[col];
#pragma unroll
    for (int Mt = 0; Mt < 4; ++Mt) {
      const size_t rowb = r0 + wm * 64 + Mt * 16 + lk * 4;
#pragma unroll
      for (int q = 0; q < 4; ++q) {
        const float p = acc[Mt][Nt][q] + bias;
        const unsigned char qb = f32_to_e4m3(p);
        PROJ8[(rowb + q) * 256 + col] = qb;
        const float d = e4m3_to_f32(qb);
        x2p[Mt][q] += d * d;
      }
    }
  }
#pragma unroll
  for (int Mt = 0; Mt < 4; ++Mt)
#pragma unroll
    for (int q = 0; q < 4; ++q) {
      float v = x2p[Mt][q];
      v += __shfl_xor(v, 1); v += __shfl_xor(v, 2);
      v += __shfl_xor(v, 4); v += __shfl_xor(v, 8);
      x2p[Mt][q] = v;
    }
  __syncthreads();
  if (lr == 0) {
#pragma unroll
    for (int Mt = 0; Mt < 4; ++Mt)
#pragma unroll
      for (int q = 0; q < 4; ++q)
        sX2[wn * 128 + wm * 64 + Mt * 16 + lk * 4 + q] = x2p[Mt][q];
  }
  __syncthreads();
  if (tid < 128)
    X2[r0 + tid] = sX2[tid] + sX2[128 + tid] + sX2[256 + tid] + sX2[384 + tid];
}

// ---------------- dist (MX-fp8, LDS-free, occupancy-optimized): 64 rows/block, Mt=4,
// grid=512 -> 2 blocks/CU = 4 waves/SIMD. A + single-buffered B fit the 128-VGPR bucket;
// cross-wave TLP hides the L2 load latency instead of per-wave double buffering.
__global__ __launch_bounds__(512, 4) void dist_kernel(const unsigned char* __restrict__ PROJ8,
                                                      const unsigned char* __restrict__ SB8,
                                                      const float* __restrict__ m2g,
                                                      const float* __restrict__ X2,
                                                      float* __restrict__ out) {
  __shared__ float minbuf[512];  // [8 waves][64 rows]

  const int tid = threadIdx.x;
  const int w = tid >> 6, lane = tid & 63;
  const int lr = lane & 15, lk = lane >> 4;
  const size_t r0 = (size_t)blockIdx.x * 64;

  // A fragments: A[Mt][h] = 32 fp8 of proj row (r0+Mt*16+lr), k = h*128 + lk*32 .. +32
  i32x8 A[4][2];
#pragma unroll
  for (int Mt = 0; Mt < 4; ++Mt)
#pragma unroll
    for (int h = 0; h < 2; ++h)
      A[Mt][h] = *(const i32x8*)(PROJ8 + (r0 + Mt * 16 + lr) * 256 + h * 128 + lk * 32);

  const char* sb = (const char*)SB8 + ((size_t)w * 2 * 64 + lane) * 32;  // + t*32768, h*2048
  const float* m2p = m2g + w * 16 + lr;                                  // + t*128

  f32x4 minv[4];
#pragma unroll
  for (int Mt = 0; Mt < 4; ++Mt)
#pragma unroll
    for (int q = 0; q < 4; ++q) minv[Mt][q] = 3.0e38f;

  for (int t = 0; t < 128; ++t) {
    const i32x8 B0 = *(const i32x8*)(sb + (size_t)t * 32768);
    const i32x8 B1 = *(const i32x8*)(sb + (size_t)t * 32768 + 2048);
    const float m2c = m2p[t * 128];

    // acc starts at m2[col]; SB8 = -2*bank, so acc ends at m2 - 2*<proj,bank>
    f32x4 acc[4];
#pragma unroll
    for (int Mt = 0; Mt < 4; ++Mt) {
      acc[Mt][0] = m2c; acc[Mt][1] = m2c; acc[Mt][2] = m2c; acc[Mt][3] = m2c;
    }
    __builtin_amdgcn_s_setprio(1);
#pragma unroll
    for (int Mt = 0; Mt < 4; ++Mt) acc[Mt] = MFMAS(A[Mt][0], B0, acc[Mt]);
#pragma unroll
    for (int Mt = 0; Mt < 4; ++Mt) acc[Mt] = MFMAS(A[Mt][1], B1, acc[Mt]);
    __builtin_amdgcn_s_setprio(0);
#pragma unroll
    for (int Mt = 0; Mt < 4; ++Mt) {
      minv[Mt][0] = fminf(minv[Mt][0], acc[Mt][0]);
      minv[Mt][1] = fminf(minv[Mt][1], acc[Mt][1]);
      minv[Mt][2] = fminf(minv[Mt][2], acc[Mt][2]);
      minv[Mt][3] = fminf(minv[Mt][3], acc[Mt][3]);
    }
  }

  // reduce min over the 16 bank-column lanes (lr); rows live at lk*4+q
#pragma unroll
  for (int Mt = 0; Mt < 4; ++Mt)
#pragma unroll
    for (int q = 0; q < 4; ++q) {
      float v = minv[Mt][q];
      v = fminf(v, __shfl_xor(v, 1)); v = fminf(v, __shfl_xor(v, 2));
      v = fminf(v, __shfl_xor(v, 4)); v = fminf(v, __shfl_xor(v, 8));
      minv[Mt][q] = v;
    }
  if (lr == 0) {
#pragma unroll
    for (int Mt = 0; Mt < 4; ++Mt)
#pragma unroll
      for (int q = 0; q < 4; ++q)
        minbuf[w * 64 + Mt * 16 + lk * 4 + q] = minv[Mt][q];
  }
  __syncthreads();
  if (tid < 64) {
    float m = minbuf[tid];
#pragma unroll
    for (int v = 1; v < 8; ++v) m = fminf(m, minbuf[v * 64 + tid]);
    const float d2 = X2[r0 + tid] + m;
    out[r0 + tid] = sqrtf(fmaxf(d2, 0.f));
  }
}

extern "C" void kernel_launch(void* const* d_in, const int* in_sizes, int n_in,
                              void* d_out, int out_size, void* d_ws, size_t ws_size,
                              hipStream_t stream) {
  const float* F = (const float*)d_in[0];
  const float* W1 = (const float*)d_in[1];
  const float* b1 = (const float*)d_in[2];
  const float* W2 = (const float*)d_in[3];
  const float* b2 = (const float*)d_in[4];
  const float* bank = (const float*)d_in[5];
  float* out = (float*)d_out;

  char* ws = (char*)d_ws;
  unsigned char* SB8 = (unsigned char*)(ws + 0);   // 4,194,304 B + 65,536 pad
  float* m2 = (float*)(ws + 4259840);              //    65,536 B +  1,024 pad
  bf16* W1t = (bf16*)(ws + 4326400);               // 1,048,576 B
  bf16* W2t = (bf16*)(ws + 5374976);               //   262,144 B
  bf16* H = (bf16*)(ws + 5637120);                 // 33,554,432 B
  unsigned char* PROJ8 = (unsigned char*)(ws + 39191552);  // 8,388,608 B
  float* X2 = (float*)(ws + 47580160);             //   131,072 B -> total 47,711,232 B

  prep_w<<<2560, 256, 0, stream>>>(W1, W2, W1t, W2t);
  prep_bank<<<4096, 256, 0, stream>>>(bank, SB8, m2);
  mlp1_kernel<<<256, 512, 0, stream>>>(F, W1t, b1, H);
  mlp2_kernel<<<256, 512, 0, stream>>>(H, W2t, b2, PROJ8, X2);
  dist_kernel<<<512, 512, 0, stream>>>(PROJ8, SB8, m2, X2, out);
}

// Round 9
// 205.823 us; speedup vs baseline: 1.5389x; 1.5389x over previous
//
#include <hip/hip_runtime.h>
#include <math.h>

typedef __bf16 bf16;
typedef __attribute__((ext_vector_type(8))) __bf16 bf16x8;
typedef __attribute__((ext_vector_type(4))) float f32x4;
typedef __attribute__((ext_vector_type(8))) int i32x8;

typedef __attribute__((address_space(1))) const void gvoid;
typedef __attribute__((address_space(3))) void lvoid;
#define GLL(g, l) __builtin_amdgcn_global_load_lds((gvoid*)(g), (lvoid*)(l), 16, 0, 0)
#define MFMA(a, b, c) __builtin_amdgcn_mfma_f32_16x16x32_bf16((a), (b), (c), 0, 0, 0)
// MX-scaled fp8 GEMM, unit scales (E8M0 0x7F = 1.0): exact same math as fp8_fp8, 2.28x rate
#define MFMAS(a, b, c) \
  __builtin_amdgcn_mfma_scale_f32_16x16x128_f8f6f4((a), (b), (c), 0, 0, 0, 0x7F, 0, 0x7F)

__device__ __forceinline__ int swz128(int row, int kb) { return kb ^ ((row & 7) << 4); }

// ---- fp8 e4m3fn encode/decode (OCP: bias 7, max 448, no inf) ----
__device__ __forceinline__ unsigned char f32_to_e4m3(float x) {
  const unsigned s = (__float_as_uint(x) >> 24) & 0x80;
  float ax = fminf(fabsf(x), 448.f);
  unsigned e;
  if (ax >= 0.015625f) {  // normal range (>= 2^-6)
    const unsigned u = __float_as_uint(ax);
    const unsigned t = u + 0x7FFFF + ((u >> 20) & 1);  // RNE to 3 mantissa bits
    e = (((t >> 23) - 120) << 3) | ((t >> 20) & 7);
  } else {  // subnormal: value = q * 2^-9, q in 0..8
    e = (unsigned)__float2int_rn(ax * 512.f);
  }
  return (unsigned char)(s | e);
}
__device__ __forceinline__ float e4m3_to_f32(unsigned char b) {
  const unsigned s = ((unsigned)b & 0x80) << 24;
  const unsigned em = b & 0x7F;
  float v;
  if (em >= 8) v = __uint_as_float((((em >> 3) + 120) << 23) | ((em & 7) << 20));
  else v = (float)em * 0.001953125f;
  return __uint_as_float(__float_as_uint(v) | s);
}

// ---------------- prep: W1 [1024][512] -> W1t bf16 [512][1024]; W2 [512][256] -> W2t [256][512]
__global__ __launch_bounds__(256) void prep_w(const float* __restrict__ W1,
                                              const float* __restrict__ W2,
                                              bf16* __restrict__ W1t, bf16* __restrict__ W2t) {
  const int t = blockIdx.x * 256 + threadIdx.x;
  if (t < 512 * 1024) {
    const int h = t & 511, k = t >> 9;
    W1t[h * 1024 + k] = (bf16)W1[k * 512 + h];
  } else {
    const int u = t - 512 * 1024;
    const int e = u & 255, k = u >> 8;
    W2t[e * 512 + k] = (bf16)W2[k * 256 + e];
  }
}

// ---------------- prep: bank fp32 [16384][256] -> SB8 = e4m3(-2*bank) repacked as a
// per-(tile, wave, half, lane) register-fragment stream:
//   SB8[(((t*8+w)*2+h)*64 + lk*16 + lr)*32 + (k & 31)]  holds bank row (t*128+w*16+lr),
//   k = h*128 + lk*32 + [0,32)  -- one i32x8 load per lane per half, fully coalesced.
// m2[row] consistent with the quantized values used in MFMA.
__global__ __launch_bounds__(256) void prep_bank(const float* __restrict__ bank,
                                                 unsigned char* __restrict__ SB8,
                                                 float* __restrict__ m2) {
  const int tid = threadIdx.x, lane = tid & 63, wv = tid >> 6;
  const int row = blockIdx.x * 4 + wv;
  const float4 v = *reinterpret_cast<const float4*>(bank + (size_t)row * 256 + lane * 4);
  uchar4 q;
  float ssum = 0.f;
  {
    const float xs[4] = {v.x, v.y, v.z, v.w};
    unsigned char qb[4];
#pragma unroll
    for (int e = 0; e < 4; ++e) {
      qb[e] = f32_to_e4m3(-2.f * xs[e]);
      const float d = e4m3_to_f32(qb[e]);
      ssum += d * d;
    }
    q.x = qb[0]; q.y = qb[1]; q.z = qb[2]; q.w = qb[3];
  }
#pragma unroll
  for (int off = 1; off < 64; off <<= 1) ssum += __shfl_xor(ssum, off);
  // k0 = lane*4: h = k0>>7, lk = (k0>>5)&3, off32 = k0&31
  const int t = row >> 7, ww = (row >> 4) & 7, lrr = row & 15;
  const int h = lane >> 5, lk = (lane >> 3) & 3, off32 = (lane & 7) * 4;
  const size_t dst = ((((size_t)t * 8 + ww) * 2 + h) * 64 + lk * 16 + lrr) * 32 + off32;
  *reinterpret_cast<uchar4*>(SB8 + dst) = q;
  if (lane == 0) m2[row] = ssum * 0.25f;  // (d/2)^2 summed
}

// ---------------- mlp1: H[32768][512] = relu(F @ W1 + b1), bf16 out
__global__ __launch_bounds__(512, 2) void mlp1_kernel(const float* __restrict__ F,
                                                      const bf16* __restrict__ W1t,
                                                      const float* __restrict__ b1,
                                                      bf16* __restrict__ H) {
  __shared__ __align__(16) char smem[81920];
  char* sA = smem;          // F chunk bf16 [128 rows][128B], swizzled
  char* sB = smem + 16384;  // W1t chunk [512 n][128B], swizzled

  const int tid = threadIdx.x;
  const int w = tid >> 6, lane = tid & 63;
  const int wm = w >> 2, wn = w & 3;
  const int lr = lane & 15, lk = lane >> 4;
  const size_t r0 = (size_t)blockIdx.x * 128;

  f32x4 acc[4][8];
  const f32x4 z = {0.f, 0.f, 0.f, 0.f};
#pragma unroll
  for (int m = 0; m < 4; ++m)
#pragma unroll
    for (int n = 0; n < 8; ++n) acc[m][n] = z;

  for (int kc = 0; kc < 16; ++kc) {
    {
      const int fr = tid >> 2, kg = (tid & 3) << 4;
      const float* fsrc = F + (r0 + fr) * 1024 + kc * 64 + kg;
      const float4 f0 = *reinterpret_cast<const float4*>(fsrc);
      const float4 f1 = *reinterpret_cast<const float4*>(fsrc + 4);
      const float4 f2 = *reinterpret_cast<const float4*>(fsrc + 8);
      const float4 f3 = *reinterpret_cast<const float4*>(fsrc + 12);
      bf16x8 p0, p1;
      p0[0] = (bf16)f0.x; p0[1] = (bf16)f0.y; p0[2] = (bf16)f0.z; p0[3] = (bf16)f0.w;
      p0[4] = (bf16)f1.x; p0[5] = (bf16)f1.y; p0[6] = (bf16)f1.z; p0[7] = (bf16)f1.w;
      p1[0] = (bf16)f2.x; p1[1] = (bf16)f2.y; p1[2] = (bf16)f2.z; p1[3] = (bf16)f2.w;
      p1[4] = (bf16)f3.x; p1[5] = (bf16)f3.y; p1[6] = (bf16)f3.z; p1[7] = (bf16)f3.w;
      const int bb = kg * 2;
      *(bf16x8*)(sA + fr * 128 + swz128(fr, bb)) = p0;
      *(bf16x8*)(sA + fr * 128 + swz128(fr, bb + 16)) = p1;
    }
#pragma unroll
    for (int i = 0; i < 8; ++i) {
      const int o = (w * 8 + i) * 1024 + lane * 16;
      const int n = o >> 7, b = o & 127;
      GLL((const char*)W1t + n * 2048 + kc * 128 + swz128(n, b), sB + (w * 8 + i) * 1024);
    }
    __syncthreads();
#pragma unroll
    for (int ks = 0; ks < 2; ++ks) {
      bf16x8 av[4];
#pragma unroll
      for (int Mt = 0; Mt < 4; ++Mt) {
        const int row = wm * 64 + Mt * 16 + lr;
        av[Mt] = *(const bf16x8*)(sA + row * 128 + swz128(row, ks * 64 + lk * 16));
      }
#pragma unroll
      for (int Nt = 0; Nt < 8; ++Nt) {
        const int n = wn * 128 + Nt * 16 + lr;
        const bf16x8 bv = *(const bf16x8*)(sB + n * 128 + swz128(n, ks * 64 + lk * 16));
#pragma unroll
        for (int Mt = 0; Mt < 4; ++Mt) acc[Mt][Nt] = MFMA(av[Mt], bv, acc[Mt][Nt]);
      }
    }
    __syncthreads();
  }
#pragma unroll
  for (int Nt = 0; Nt < 8; ++Nt) {
    const int col = wn * 128 + Nt * 16 + lr;
    const float bias = b1[col];
#pragma unroll
    for (int Mt = 0; Mt < 4; ++Mt) {
      const size_t rowb = r0 + wm * 64 + Mt * 16 + lk * 4;
#pragma unroll
      for (int q = 0; q < 4; ++q)
        H[(rowb + q) * 512 + col] = (bf16)fmaxf(acc[Mt][Nt][q] + bias, 0.f);
    }
  }
}

// ---------------- mlp2: PROJ8[32768][256] fp8 = e4m3(H @ W2 + b2); X2 from decoded fp8
__global__ __launch_bounds__(512, 2) void mlp2_kernel(const bf16* __restrict__ H,
                                                      const bf16* __restrict__ W2t,
                                                      const float* __restrict__ b2,
                                                      unsigned char* __restrict__ PROJ8,
                                                      float* __restrict__ X2) {
  __shared__ __align__(16) char smem[51200];
  char* sA = smem;                        // H chunk [128][128B] swizzled
  char* sB = smem + 16384;                // W2t chunk [256][128B] swizzled
  float* sX2 = (float*)(smem + 49152);    // [4][128]

  const int tid = threadIdx.x;
  const int w = tid >> 6, lane = tid & 63;
  const int wm = w >> 2, wn = w & 3;
  const int lr = lane & 15, lk = lane >> 4;
  const size_t r0 = (size_t)blockIdx.x * 128;

  f32x4 acc[4][4];
  const f32x4 z = {0.f, 0.f, 0.f, 0.f};
#pragma unroll
  for (int m = 0; m < 4; ++m)
#pragma unroll
    for (int n = 0; n < 4; ++n) acc[m][n] = z;

  for (int kc = 0; kc < 8; ++kc) {
#pragma unroll
    for (int i = 0; i < 2; ++i) {
      const int o = (w * 2 + i) * 1024 + lane * 16;
      const int row = o >> 7, b = o & 127;
      GLL((const char*)H + (r0 + row) * 1024 + kc * 128 + swz128(row, b), sA + (w * 2 + i) * 1024);
    }
#pragma unroll
    for (int i = 0; i < 4; ++i) {
      const int o = (w * 4 + i) * 1024 + lane * 16;
      const int n = o >> 7, b = o & 127;
      GLL((const char*)W2t + n * 1024 + kc * 128 + swz128(n, b), sB + (w * 4 + i) * 1024);
    }
    __syncthreads();
#pragma unroll
    for (int ks = 0; ks < 2; ++ks) {
      bf16x8 av[4];
#pragma unroll
      for (int Mt = 0; Mt < 4; ++Mt) {
        const int row = wm * 64 + Mt * 16 + lr;
        av[Mt] = *(const bf16x8*)(sA + row * 128 + swz128(row, ks * 64 + lk * 16));
      }
#pragma unroll
      for (int Nt = 0; Nt < 4; ++Nt) {
        const int n = wn * 64 + Nt * 16 + lr;
        const bf16x8 bv = *(const bf16x8*)(sB + n * 128 + swz128(n, ks * 64 + lk * 16));
#pragma unroll
        for (int Mt = 0; Mt < 4; ++Mt) acc[Mt][Nt] = MFMA(av[Mt], bv, acc[Mt][Nt]);
      }
    }
    __syncthreads();
  }
  // epilogue: +b2, quantize to fp8, store PROJ8, accumulate consistent x2
  float x2p[4][4];
#pragma unroll
  for (int m = 0; m < 4; ++m)
#pragma unroll
    for (int q = 0; q < 4; ++q) x2p[m][q] = 0.f;
#pragma unroll
  for (int Nt = 0; Nt < 4; ++Nt) {
    const int col = wn * 64 + Nt * 16 + lr;
    const float bias = b2[col];
#pragma unroll
    for (int Mt = 0; Mt < 4; ++Mt) {
      const size_t rowb = r0 + wm * 64 + Mt * 16 + lk * 4;
#pragma unroll
      for (int q = 0; q < 4; ++q) {
        const float p = acc[Mt][Nt][q] + bias;
        const unsigned char qb = f32_to_e4m3(p);
        PROJ8[(rowb + q) * 256 + col] = qb;
        const float d = e4m3_to_f32(qb);
        x2p[Mt][q] += d * d;
      }
    }
  }
#pragma unroll
  for (int Mt = 0; Mt < 4; ++Mt)
#pragma unroll
    for (int q = 0; q < 4; ++q) {
      float v = x2p[Mt][q];
      v += __shfl_xor(v, 1); v += __shfl_xor(v, 2);
      v += __shfl_xor(v, 4); v += __shfl_xor(v, 8);
      x2p[Mt][q] = v;
    }
  __syncthreads();
  if (lr == 0) {
#pragma unroll
    for (int Mt = 0; Mt < 4; ++Mt)
#pragma unroll
      for (int q = 0; q < 4; ++q)
        sX2[wn * 128 + wm * 64 + Mt * 16 + lk * 4 + q] = x2p[Mt][q];
  }
  __syncthreads();
  if (tid < 128)
    X2[r0 + tid] = sX2[tid] + sX2[128 + tid] + sX2[256 + tid] + sX2[384 + tid];
}

// ---------------- dist (MX-fp8, LDS-free, deep reg pipeline): 64 rows/block (Mt=4),
// grid=512, launch_bounds(512,2) -- generous 256-VGPR cap, NO spill (r8 lesson).
// 4-slot NAMED register ring (rule #20: no runtime indexing), depth-3 prefetch covers
// the ~900cyc HBM first-touch latency on the SB8 stream. SB8/m2 padded by 4 dummy tiles.
__global__ __launch_bounds__(512, 2) void dist_kernel(const unsigned char* __restrict__ PROJ8,
                                                      const unsigned char* __restrict__ SB8,
                                                      const float* __restrict__ m2g,
                                                      const float* __restrict__ X2,
                                                      float* __restrict__ out) {
  __shared__ float minbuf[512];  // [8 waves][64 rows]

  const int tid = threadIdx.x;
  const int w = tid >> 6, lane = tid & 63;
  const int lr = lane & 15, lk = lane >> 4;
  const size_t r0 = (size_t)blockIdx.x * 64;

  // A fragments: A[Mt][h] = 32 fp8 of proj row (r0+Mt*16+lr), k = h*128 + lk*32 .. +32
  i32x8 A[4][2];
#pragma unroll
  for (int Mt = 0; Mt < 4; ++Mt)
#pragma unroll
    for (int h = 0; h < 2; ++h)
      A[Mt][h] = *(const i32x8*)(PROJ8 + (r0 + Mt * 16 + lr) * 256 + h * 128 + lk * 32);

  const char* sb = (const char*)SB8 + ((size_t)w * 2 * 64 + lane) * 32;  // + t*32768, h*2048
  const float* m2p = m2g + w * 16 + lr;                                  // + t*128

  f32x4 minv[4];
#pragma unroll
  for (int Mt = 0; Mt < 4; ++Mt)
#pragma unroll
    for (int q = 0; q < 4; ++q) minv[Mt][q] = 3.0e38f;

#define LOADT(B0, B1, MC, tt)                                \
  do {                                                       \
    B0 = *(const i32x8*)(sb + (size_t)(tt) * 32768);         \
    B1 = *(const i32x8*)(sb + (size_t)(tt) * 32768 + 2048);  \
    MC = m2p[(tt) * 128];                                    \
  } while (0)

#define COMPUTE(B0, B1, MC)                                                       \
  do {                                                                            \
    f32x4 acc[4];                                                                 \
    _Pragma("unroll") for (int Mt = 0; Mt < 4; ++Mt) {                            \
      acc[Mt][0] = (MC); acc[Mt][1] = (MC); acc[Mt][2] = (MC); acc[Mt][3] = (MC); \
    }                                                                             \
    __builtin_amdgcn_s_setprio(1);                                                \
    _Pragma("unroll") for (int Mt = 0; Mt < 4; ++Mt)                              \
      acc[Mt] = MFMAS(A[Mt][0], (B0), acc[Mt]);                                   \
    _Pragma("unroll") for (int Mt = 0; Mt < 4; ++Mt)                              \
      acc[Mt] = MFMAS(A[Mt][1], (B1), acc[Mt]);                                   \
    __builtin_amdgcn_s_setprio(0);                                                \
    _Pragma("unroll") for (int Mt = 0; Mt < 4; ++Mt) {                            \
      minv[Mt][0] = fminf(minv[Mt][0], acc[Mt][0]);                               \
      minv[Mt][1] = fminf(minv[Mt][1], acc[Mt][1]);                               \
      minv[Mt][2] = fminf(minv[Mt][2], acc[Mt][2]);                               \
      minv[Mt][3] = fminf(minv[Mt][3], acc[Mt][3]);                               \
    }                                                                             \
  } while (0)

  // prologue: preload tiles 0,1,2 into slots a,b,c
  i32x8 a0, a1, b0, b1, c0, c1, d0, d1;
  float ma, mb, mc, md;
  LOADT(a0, a1, ma, 0);
  LOADT(b0, b1, mb, 1);
  LOADT(c0, c1, mc, 2);

  for (int t = 0; t < 128; t += 4) {
    LOADT(d0, d1, md, t + 3);
    __builtin_amdgcn_sched_barrier(0);
    COMPUTE(a0, a1, ma);
    LOADT(a0, a1, ma, t + 4);
    __builtin_amdgcn_sched_barrier(0);
    COMPUTE(b0, b1, mb);
    LOADT(b0, b1, mb, t + 5);
    __builtin_amdgcn_sched_barrier(0);
    COMPUTE(c0, c1, mc);
    LOADT(c0, c1, mc, t + 6);
    __builtin_amdgcn_sched_barrier(0);
    COMPUTE(d0, d1, md);
  }
#undef LOADT
#undef COMPUTE

  // reduce min over the 16 bank-column lanes (lr); rows live at lk*4+q
#pragma unroll
  for (int Mt = 0; Mt < 4; ++Mt)
#pragma unroll
    for (int q = 0; q < 4; ++q) {
      float v = minv[Mt][q];
      v = fminf(v, __shfl_xor(v, 1)); v = fminf(v, __shfl_xor(v, 2));
      v = fminf(v, __shfl_xor(v, 4)); v = fminf(v, __shfl_xor(v, 8));
      minv[Mt][q] = v;
    }
  if (lr == 0) {
#pragma unroll
    for (int Mt = 0; Mt < 4; ++Mt)
#pragma unroll
      for (int q = 0; q < 4; ++q)
        minbuf[w * 64 + Mt * 16 + lk * 4 + q] = minv[Mt][q];
  }
  __syncthreads();
  if (tid < 64) {
    float m = minbuf[tid];
#pragma unroll
    for (int v = 1; v < 8; ++v) m = fminf(m, minbuf[v * 64 + tid]);
    const float d2 = X2[r0 + tid] + m;
    out[r0 + tid] = sqrtf(fmaxf(d2, 0.f));
  }
}

extern "C" void kernel_launch(void* const* d_in, const int* in_sizes, int n_in,
                              void* d_out, int out_size, void* d_ws, size_t ws_size,
                              hipStream_t stream) {
  const float* F = (const float*)d_in[0];
  const float* W1 = (const float*)d_in[1];
  const float* b1 = (const float*)d_in[2];
  const float* W2 = (const float*)d_in[3];
  const float* b2 = (const float*)d_in[4];
  const float* bank = (const float*)d_in[5];
  float* out = (float*)d_out;

  char* ws = (char*)d_ws;
  unsigned char* SB8 = (unsigned char*)(ws + 0);   // 4,194,304 B + 131,072 pad (4 dummy tiles)
  float* m2 = (float*)(ws + 4325376);              //    65,536 B +   2,048 pad
  bf16* W1t = (bf16*)(ws + 4392960);               // 1,048,576 B
  bf16* W2t = (bf16*)(ws + 5441536);               //   262,144 B
  bf16* H = (bf16*)(ws + 5703680);                 // 33,554,432 B
  unsigned char* PROJ8 = (unsigned char*)(ws + 39258112);  // 8,388,608 B
  float* X2 = (float*)(ws + 47646720);             //   131,072 B -> total 47,777,792 B

  prep_w<<<2560, 256, 0, stream>>>(W1, W2, W1t, W2t);
  prep_bank<<<4096, 256, 0, stream>>>(bank, SB8, m2);
  mlp1_kernel<<<256, 512, 0, stream>>>(F, W1t, b1, H);
  mlp2_kernel<<<256, 512, 0, stream>>>(H, W2t, b2, PROJ8, X2);
  dist_kernel<<<512, 512, 0, stream>>>(PROJ8, SB8, m2, X2, out);
}